// Round 6
// baseline (159.884 us; speedup 1.0000x reference)
//
#include <hip/hip_runtime.h>
#include <hip/hip_bf16.h>

typedef __attribute__((ext_vector_type(8))) short short8;
typedef __attribute__((ext_vector_type(4))) float floatx4;

#define N_ROWS 8192
#define C_DIM  128
#define CHUNK  512                         /* cols per block */
#define NIT    (CHUNK / 64)                /* 8 col-tiles of 64 */
#define NBLK   (1024 + 544 + 544)
#define KSCALE 14.426950408889634f         /* 10 * log2(e) */
#define LN2    0.6931471805599453f

__device__ __forceinline__ unsigned int pack_bf16x2(float x, float y) {
    union { float f; unsigned int u; } a, b;
    a.f = x; b.f = y;
    unsigned int ra = a.u + 0x7FFFu + ((a.u >> 16) & 1u);
    unsigned int rb = b.u + 0x7FFFu + ((b.u >> 16) & 1u);
    return (ra >> 16) | ((rb >> 16) << 16);
}
__device__ __forceinline__ float bf2f(unsigned short s) {
    union { unsigned int u; float f; } x; x.u = ((unsigned int)s) << 16;
    return x.f;
}

// One wave per row-pair (img_r, mol_r): normalize both to bf16, store W,
// compute diag dots d00/d01/d11 on the QUANTIZED values -> D. Zero SE/cnt.
__global__ __launch_bounds__(256) void norm_kernel(
    const float* __restrict__ img, const float* __restrict__ mol,
    unsigned short* __restrict__ W, float* __restrict__ SE,
    float* __restrict__ D, unsigned int* __restrict__ cnt)
{
    if (blockIdx.x < 32) {                         // zero SE[4][8192]
        int t = blockIdx.x * 1024 + threadIdx.x;
        SE[t] = 0.f; SE[t + 256] = 0.f; SE[t + 512] = 0.f; SE[t + 768] = 0.f;
        if (blockIdx.x == 0 && threadIdx.x == 0) *cnt = 0u;
    }
    int wave = threadIdx.x >> 6, lane = threadIdx.x & 63;
    int row = blockIdx.x * 4 + wave;               // 0..8191
    float2 va = *reinterpret_cast<const float2*>(img + (size_t)row * C_DIM + lane * 2);
    float2 vb = *reinterpret_cast<const float2*>(mol + (size_t)row * C_DIM + lane * 2);
    float sa = va.x * va.x + va.y * va.y;
    float sb = vb.x * vb.x + vb.y * vb.y;
    #pragma unroll
    for (int m = 1; m < 64; m <<= 1) {
        sa += __shfl_xor(sa, m);
        sb += __shfl_xor(sb, m);
    }
    float ia = rsqrtf(sa), ib = rsqrtf(sb);
    unsigned int pa = pack_bf16x2(va.x * ia, va.y * ia);
    unsigned int pb = pack_bf16x2(vb.x * ib, vb.y * ib);
    ((unsigned int*)(W + (size_t)row * C_DIM))[lane] = pa;
    ((unsigned int*)(W + (size_t)(N_ROWS + row) * C_DIM))[lane] = pb;
    float a0 = bf2f((unsigned short)pa), a1 = bf2f((unsigned short)(pa >> 16));
    float b0 = bf2f((unsigned short)pb), b1 = bf2f((unsigned short)(pb >> 16));
    float d00 = a0 * a0 + a1 * a1;
    float d01 = a0 * b0 + a1 * b1;
    float d11 = b0 * b0 + b1 * b1;
    #pragma unroll
    for (int m = 1; m < 64; m <<= 1) {
        d00 += __shfl_xor(d00, m);
        d01 += __shfl_xor(d01, m);
        d11 += __shfl_xor(d11, m);
    }
    if (lane == 0) {
        D[row] = d00;
        D[N_ROWS + row] = d01;
        D[2 * N_ROWS + row] = d11;
    }
}

// Symmetric-aware pass + fused finalize (last-block completion counter).
__global__ __launch_bounds__(256) void pass_kernel(
    const unsigned short* __restrict__ W, float* __restrict__ SE,
    const float* __restrict__ D, unsigned int* __restrict__ cnt,
    float* __restrict__ out)
{
    __shared__ unsigned short buf[2][64][128];     // 2 x 16 KB
    __shared__ float colbuf[4][CHUNK];             // per-wave col sums, 8 KB
    __shared__ bool islast;
    __shared__ float red[4];

    int idx = blockIdx.x;
    const unsigned short *X, *Y;
    float *rowSE, *colSE;
    bool dual;
    int rb, ch;
    if (idx < 1024) {
        rb = idx >> 4; ch = idx & 15;
        X = W; Y = W + (size_t)N_ROWS * C_DIM;
        rowSE = SE + 1 * N_ROWS; colSE = SE + 3 * N_ROWS; dual = true;
    } else {
        int j = idx - 1024;
        const unsigned short* M = (j < 544) ? W : W + (size_t)N_ROWS * C_DIM;
        float* S = (j < 544) ? SE : SE + 2 * N_ROWS;
        if (j >= 544) j -= 544;
        X = M; Y = M; rowSE = S; colSE = S;
        if (j < 64) { rb = j; ch = rb >> 2; dual = false; }
        else {
            int j2 = j - 64, p = j2 >> 2;
            int si = 0, cum = 15;
            while (p >= cum) { p -= cum; ++si; cum = 15 - si; }
            int sj = si + 1 + p;
            rb = si * 4 + (j2 & 3); ch = sj; dual = true;
        }
    }

    int lane = threadIdx.x & 63, wave = threadIdx.x >> 6;
    int l15 = lane & 15, lg = lane >> 4;
    int rbase = rb * 128 + wave * 32;
    int cstart = ch * CHUNK;

    short8 af[2][4];
    #pragma unroll
    for (int m = 0; m < 2; ++m)
        #pragma unroll
        for (int k = 0; k < 4; ++k)
            af[m][k] = *reinterpret_cast<const short8*>(
                X + (size_t)(rbase + m * 16 + l15) * C_DIM + k * 32 + lg * 8);

    auto stage = [&](int bsel, int jb) {
        #pragma unroll
        for (int i = 0; i < 4; ++i) {
            int c = i * 4 + wave;                  // 1KB chunk 0..15
            int r = c * 4 + lg;                    // tile row 0..63
            int s = l15 ^ (r & 15);                // full 16-slot XOR swizzle
            const void* gsrc = (const char*)Y + (size_t)(cstart + jb + r) * 256 + s * 16;
            void* ldst = (char*)&buf[bsel][0][0] + c * 1024;
            __builtin_amdgcn_global_load_lds(
                (const __attribute__((address_space(1))) unsigned int*)gsrc,
                (__attribute__((address_space(3))) unsigned int*)ldst,
                16, 0, 0);
        }
    };

    float se[2][4] = {{0.f,0.f,0.f,0.f},{0.f,0.f,0.f,0.f}};

    stage(0, 0);
    int cur = 0;
    for (int it = 0; it < NIT; ++it) {
        if (it + 1 < NIT) {
            stage(cur ^ 1, (it + 1) * 64);
            asm volatile("s_waitcnt vmcnt(4)" ::: "memory");
        } else {
            asm volatile("s_waitcnt vmcnt(0)" ::: "memory");
        }
        __builtin_amdgcn_s_barrier();
        asm volatile("" ::: "memory");

        float ce[4] = {0.f, 0.f, 0.f, 0.f};
        #pragma unroll
        for (int n = 0; n < 4; ++n) {
            short8 bk[4];
            #pragma unroll
            for (int k = 0; k < 4; ++k) {
                int row = n * 16 + l15;
                int s = (k * 4 + lg) ^ l15;        // un-swizzle on read
                bk[k] = *reinterpret_cast<const short8*>(
                    (const char*)&buf[cur][0][0] + row * 256 + s * 16);
            }
            #pragma unroll
            for (int m = 0; m < 2; ++m) {
                floatx4 acc = {0.f, 0.f, 0.f, 0.f};
                #pragma unroll
                for (int k = 0; k < 4; ++k)
                    acc = __builtin_amdgcn_mfma_f32_16x16x32_bf16(
                              af[m][k], bk[k], acc, 0, 0, 0);
                #pragma unroll
                for (int r = 0; r < 4; ++r) {
                    float e = __builtin_amdgcn_exp2f(acc[r] * KSCALE - KSCALE);
                    se[m][r] += e;
                    ce[n] += e;
                }
            }
        }
        if (dual) {
            #pragma unroll
            for (int n = 0; n < 4; ++n) {
                float c2 = ce[n];
                c2 += __shfl_xor(c2, 16);
                c2 += __shfl_xor(c2, 32);
                if (lg == 0)
                    colbuf[wave][it * 64 + n * 16 + l15] = c2;  // plain store
            }
        }
        asm volatile("s_waitcnt lgkmcnt(0)" ::: "memory");
        __builtin_amdgcn_sched_barrier(0);
        __builtin_amdgcn_s_barrier();
        cur ^= 1;
    }

    // row sums -> rowSE
    #pragma unroll
    for (int m = 0; m < 2; ++m)
        #pragma unroll
        for (int r = 0; r < 4; ++r) {
            float s = se[m][r];
            s += __shfl_xor(s, 1);
            s += __shfl_xor(s, 2);
            s += __shfl_xor(s, 4);
            s += __shfl_xor(s, 8);
            if (l15 == 0)
                atomicAdd(&rowSE[rbase + m * 16 + lg * 4 + r], s);
        }
    // col sums -> colSE (all waves' colbuf complete: loop-end barrier)
    if (dual)
        for (int c = threadIdx.x; c < CHUNK; c += 256)
            atomicAdd(&colSE[cstart + c],
                      colbuf[0][c] + colbuf[1][c] + colbuf[2][c] + colbuf[3][c]);

    // ---- completion counter: last block finalizes ----
    __syncthreads();
    if (threadIdx.x == 0) {
        __threadfence();
        unsigned int old = atomicAdd(cnt, 1u);
        islast = (old == NBLK - 1);
    }
    __syncthreads();
    if (!islast) return;

    float local = 0.f;
    for (int r = threadIdx.x; r < N_ROWS; r += 256) {
        float d00 = D[r], d01 = D[N_ROWS + r], d11 = D[2 * N_ROWS + r];
        float e00 = __builtin_amdgcn_exp2f(KSCALE * (d00 - 1.f));
        float e01 = __builtin_amdgcn_exp2f(KSCALE * (d01 - 1.f));
        float e11 = __builtin_amdgcn_exp2f(KSCALE * (d11 - 1.f));
        float s0 = __hip_atomic_load(&SE[r], __ATOMIC_RELAXED,
                                     __HIP_MEMORY_SCOPE_AGENT) - e00;
        float s1 = __hip_atomic_load(&SE[N_ROWS + r], __ATOMIC_RELAXED,
                                     __HIP_MEMORY_SCOPE_AGENT) - e01;
        float s2 = __hip_atomic_load(&SE[2 * N_ROWS + r], __ATOMIC_RELAXED,
                                     __HIP_MEMORY_SCOPE_AGENT) - e11;
        float s3 = __hip_atomic_load(&SE[3 * N_ROWS + r], __ATOMIC_RELAXED,
                                     __HIP_MEMORY_SCOPE_AGENT) - e01;
        float lg4 = __builtin_amdgcn_logf(s0) + __builtin_amdgcn_logf(s1)
                  + __builtin_amdgcn_logf(s2) + __builtin_amdgcn_logf(s3);
        local += -10.f * d01 + 0.5f * LN2 * lg4 + 20.f;
    }
    #pragma unroll
    for (int m = 1; m < 64; m <<= 1) local += __shfl_xor(local, m);
    if (lane == 0) red[wave] = local;
    __syncthreads();
    if (threadIdx.x == 0)
        *out = (red[0] + red[1] + red[2] + red[3]) * (1.0f / N_ROWS);
}

extern "C" void kernel_launch(void* const* d_in, const int* in_sizes, int n_in,
                              void* d_out, int out_size, void* d_ws, size_t ws_size,
                              hipStream_t stream)
{
    const float* img = (const float*)d_in[0];
    const float* mol = (const float*)d_in[1];
    float* out = (float*)d_out;
    unsigned short* W = (unsigned short*)d_ws;                    // 4 MB bf16 A|B
    char* base = (char*)d_ws + (size_t)2 * N_ROWS * C_DIM * 2;
    float* SE = (float*)base;                                     // 128 KB
    float* D  = (float*)(base + 4 * N_ROWS * sizeof(float));      // 96 KB
    unsigned int* cnt = (unsigned int*)(base + 7 * N_ROWS * sizeof(float));

    norm_kernel<<<dim3(N_ROWS / 4), 256, 0, stream>>>(img, mol, W, SE, D, cnt);
    pass_kernel<<<dim3(NBLK), 256, 0, stream>>>(W, SE, D, cnt, out);
}